// Round 16
// baseline (831.517 us; speedup 1.0000x reference)
//
#include <hip/hip_runtime.h>

#define NNODES 200000
#define MPAD   200064   // NNODES rounded up to 128
#define NEDGES 400000
#define FIN    165
#define K1P    192      // FIN padded to 6 x 32
#define HID    512
#define NB     ((NNODES + 255) / 256)   // 782 scan blocks

typedef __bf16 bf16_t;
typedef __bf16 bf16x8 __attribute__((ext_vector_type(8)));
typedef float  f32x4  __attribute__((ext_vector_type(4)));
typedef unsigned short su16x8 __attribute__((ext_vector_type(8)));
typedef float f32x4u __attribute__((ext_vector_type(4), aligned(4)));

static __device__ __forceinline__ float bf2f(unsigned short u) {
    unsigned int x = ((unsigned int)u) << 16;
    return __builtin_bit_cast(float, x);
}
static __device__ __forceinline__ unsigned short f2bf(float f) {
    bf16_t h = (bf16_t)f;  // RNE
    return __builtin_bit_cast(unsigned short, h);
}
// async global->LDS, 16B per lane (dest = wave-uniform base + lane*16)
static __device__ __forceinline__ void gl_lds16(const void* g, void* l) {
    __builtin_amdgcn_global_load_lds(
        (const __attribute__((address_space(1))) unsigned int*)g,
        (__attribute__((address_space(3))) unsigned int*)l, 16, 0, 0);
}
// counted waits (per-wave); sched_barrier keeps compiler from hoisting across (rule #18)
static __device__ __forceinline__ void wait_vmcnt8() {
    asm volatile("s_waitcnt vmcnt(8)" ::: "memory");
    __builtin_amdgcn_sched_barrier(0);
}
static __device__ __forceinline__ void wait_vmcnt0() {
    asm volatile("s_waitcnt vmcnt(0)" ::: "memory");
    __builtin_amdgcn_sched_barrier(0);
}
// m204 bijective XCD-chunked swizzle
static __device__ __forceinline__ int xcd_swz(int i, int nb) {
    int q = nb >> 3, r = nb & 7;
    int xcd = i & 7, seq = i >> 3;
    return (xcd < r ? xcd * (q + 1) : r * (q + 1) + (xcd - r) * q) + seq;
}

// ---------------- degree histograms ----------------
__global__ void k_deg(const int* __restrict__ src, const int* __restrict__ dst,
                      int* __restrict__ deg, int* __restrict__ cnt, int E) {
    int e = blockIdx.x * 256 + threadIdx.x;
    if (e < E) {
        atomicAdd(&deg[src[e]], 1);
        atomicAdd(&cnt[dst[e]], 1);
    }
}

// ---------------- CSR build: 2-level exclusive scan ----------------
__global__ void k_scan1(int* __restrict__ cnt, int* __restrict__ btot, int n) {
    __shared__ int s[256];
    int i = blockIdx.x * 256 + threadIdx.x;
    int v = (i < n) ? cnt[i] : 0;
    s[threadIdx.x] = v;
    __syncthreads();
    #pragma unroll
    for (int off = 1; off < 256; off <<= 1) {
        int t = (threadIdx.x >= off) ? s[threadIdx.x - off] : 0;
        __syncthreads();
        s[threadIdx.x] += t;
        __syncthreads();
    }
    if (i < n) cnt[i] = s[threadIdx.x] - v;
    if (threadIdx.x == 255) btot[blockIdx.x] = s[255];
}

__global__ void k_scan2(int* __restrict__ btot, int nb) {
    __shared__ int s[1024];
    int i = threadIdx.x;
    int v = (i < nb) ? btot[i] : 0;
    s[i] = v;
    __syncthreads();
    #pragma unroll
    for (int off = 1; off < 1024; off <<= 1) {
        int t = (i >= off) ? s[i - off] : 0;
        __syncthreads();
        s[i] += t;
        __syncthreads();
    }
    if (i < nb) btot[i] = s[i] - v;
}

__global__ void k_scan3(int* __restrict__ cnt, const int* __restrict__ btot,
                        int* __restrict__ rowptr, int n, int E) {
    int i = blockIdx.x * 256 + threadIdx.x;
    if (i < n) {
        rowptr[i] = cnt[i] + btot[blockIdx.x];
        cnt[i] = 0;
    }
    if (i == 0) rowptr[n] = E;
}

// scatter edge -> CSR slot; precompute edge weight; optionally init out=bl (E==2*NNODES)
__global__ void k_scatter(const int* __restrict__ src, const int* __restrict__ dst,
                          const int* __restrict__ rowptr, int* __restrict__ cur,
                          const int* __restrict__ deg, int* __restrict__ esrc,
                          float* __restrict__ ew, float* __restrict__ outinit,
                          const float* __restrict__ bl, int E) {
    int e = blockIdx.x * 256 + threadIdx.x;
    if (e < E) {
        int s = src[e], d = dst[e];
        int pos = rowptr[d] + atomicAdd(&cur[d], 1);
        esrc[pos] = s;
        if (ew) {
            int da = deg[s], db = deg[d];
            float fa = da > 0 ? rsqrtf((float)da) : 0.f;
            float fb = db > 0 ? rsqrtf((float)db) : 0.f;
            ew[pos] = -fa * fb;
        }
        if (outinit) outinit[e] = bl[e & 1];
    }
}

// ---------------- build BOTH k-tiled bf16 B panels of layer 1 in one launch ----------
__global__ void k_buildP1(const float* __restrict__ W0, const float* __restrict__ W1,
                          unsigned short* __restrict__ P) {
    int idx = blockIdx.x * 256 + threadIdx.x;   // 2 * K1P * HID
    if (idx >= 2 * K1P * HID) return;
    int panel = idx / (K1P * HID);
    int rem   = idx - panel * (K1P * HID);
    int j  = rem & 7;
    int n  = (rem >> 3) & 511;
    int q  = (rem >> 12) & 3;
    int kt = rem >> 14;
    int k  = kt * 32 + q * 8 + j;
    const float* W = panel ? W1 : W0;
    P[idx] = (k < FIN) ? f2bf(W[(size_t)k * HID + n]) : (unsigned short)0;
}

// fallback single-panel builder (kp x 512)
__global__ void k_buildP(const float* __restrict__ W, unsigned short* __restrict__ P,
                         int kp, int kfull) {
    int idx = blockIdx.x * 256 + threadIdx.x;
    if (idx >= kp * HID) return;
    int j  = idx & 7;
    int n  = (idx >> 3) & 511;
    int q  = (idx >> 12) & 3;
    int kt = idx >> 14;
    int k  = kt * 32 + q * 8 + j;
    P[idx] = (k < kfull) ? f2bf(W[(size_t)k * HID + n]) : (unsigned short)0;
}

// concat panel for layer 2: K=1024, k<512 -> W2_0[k][n], else W2_1[k-512][n]
__global__ void k_buildP2cat(const float* __restrict__ W0, const float* __restrict__ W1,
                             unsigned short* __restrict__ P) {
    int idx = blockIdx.x * 256 + threadIdx.x;   // 1024*512 elems
    if (idx >= 1024 * HID) return;
    int j  = idx & 7;
    int n  = (idx >> 3) & 511;
    int q  = (idx >> 12) & 3;
    int kt = idx >> 14;
    int k  = kt * 32 + q * 8 + j;
    float v = (k < HID) ? W0[(size_t)k * HID + n] : W1[(size_t)(k - HID) * HID + n];
    P[idx] = f2bf(v);
}

// ---------------- x -> bf16 padded [MPAD x 192] ----------------
__global__ void k_xcvt(const float* __restrict__ x, unsigned short* __restrict__ xb) {
    long i = ((long)blockIdx.x * 256 + threadIdx.x) * 8;
    if (i >= (long)NNODES * K1P) return;
    int row = (int)(i / K1P), k = (int)(i % K1P);
    const float* xr = x + (size_t)row * FIN;
    __align__(16) unsigned short v[8];
    #pragma unroll
    for (int j = 0; j < 8; ++j)
        v[j] = (k + j < FIN) ? f2bf(xr[k + j]) : (unsigned short)0;
    *(su16x8*)&xb[i] = *(su16x8*)v;
}

// ---------------- k_gemms: 128x128-tile GEMM, 1D XCD-swizzled grid, BK=64 -------------
// (round-14 proven single-buffer structure; used for layer 1, K=192: 3 k-tiles)
template<int K, int LDA, int NCMB>
__global__ __launch_bounds__(256, 4)
void k_gemms(const unsigned short* __restrict__ A, const unsigned short* __restrict__ P,
             unsigned short* __restrict__ D0, unsigned short* __restrict__ D1,
             int os0, int os1, int ob0, int ob1) {
    constexpr int KT2 = K / 64;
    __shared__ unsigned short Al[128 * 64];     // 16 KB
    __shared__ unsigned short Bl[2][4][1024];   // 16 KB

    const int t    = threadIdx.x;
    const int lane = t & 63;
    const int wv   = t >> 6;
    const int wm   = wv >> 1, wn = wv & 1;
    const int wg   = xcd_swz(blockIdx.x, gridDim.x);
    const int combo = wg & (NCMB - 1);
    const int sel  = combo >> 2;
    const int ncol = (combo & 3) * 128;
    const int m0   = (wg / NCMB) * 128;
    const unsigned short* Pb = P + (size_t)sel * K * 512 + ncol * 8;
    unsigned short* D = sel ? D1 : D0;
    const int os = sel ? os1 : os0;
    const int oc = (sel ? ob1 : ob0) + ncol;

    const unsigned short* Ab = A + (size_t)m0 * LDA;
    const int ar0 = t >> 3;
    const int ach = t & 7;

    f32x4 acc[4][4];
    #pragma unroll
    for (int m = 0; m < 4; ++m)
        #pragma unroll
        for (int n = 0; n < 4; ++n)
            acc[m][n] = (f32x4){0.f, 0.f, 0.f, 0.f};

    for (int kt = 0; kt < KT2; ++kt) {
        __syncthreads();
        #pragma unroll
        for (int i = 0; i < 4; ++i) {
            int r = i * 32 + ar0;
            gl_lds16(Ab + (size_t)r * LDA + kt * 64 + (ach ^ (r & 7)) * 8,
                     &Al[i * 2048 + t * 8]);
        }
        #pragma unroll
        for (int h = 0; h < 2; ++h)
            #pragma unroll
            for (int i = 0; i < 2; ++i)
                gl_lds16(Pb + (size_t)(kt * 2 + h) * 16384 + wv * 4096 + lane * 8 + i * 512,
                         &Bl[h][wv][lane * 8 + i * 512]);
        __syncthreads();

        const int kq = lane >> 4;
        #pragma unroll
        for (int ks = 0; ks < 2; ++ks) {
            bf16x8 af[4], bfr[4];
            #pragma unroll
            for (int m = 0; m < 4; ++m) {
                int r = wm * 64 + m * 16 + (lane & 15);
                int c = ks * 4 + kq;
                af[m] = *(const bf16x8*)&Al[r * 64 + (c ^ (r & 7)) * 8];
            }
            #pragma unroll
            for (int n = 0; n < 4; ++n) {
                int c = wn * 64 + n * 16 + (lane & 15);
                bfr[n] = *(const bf16x8*)&Bl[ks][kq][c * 8];
            }
            #pragma unroll
            for (int m = 0; m < 4; ++m)
                #pragma unroll
                for (int n = 0; n < 4; ++n)
                    acc[m][n] = __builtin_amdgcn_mfma_f32_16x16x32_bf16(bfr[n], af[m], acc[m][n], 0, 0, 0);
        }
    }

    #pragma unroll
    for (int m = 0; m < 4; ++m) {
        int r = m0 + wm * 64 + m * 16 + (lane & 15);
        #pragma unroll
        for (int n = 0; n < 4; ++n) {
            int cb = oc + wn * 64 + n * 16 + (lane >> 4) * 4;
            uint2 pk;
            pk.x = ((unsigned int)f2bf(acc[m][n][1]) << 16) | (unsigned int)f2bf(acc[m][n][0]);
            pk.y = ((unsigned int)f2bf(acc[m][n][3]) << 16) | (unsigned int)f2bf(acc[m][n][2]);
            *(uint2*)&D[(size_t)r * os + cb] = pk;
        }
    }
}

// ---------------- k_gemmf: K=1024 concat GEMM, counted-vmcnt 2-phase pipeline ---------
// Double-buffered (64KB LDS, 2 blocks/CU). Raw s_barrier + vmcnt(8): tile kt+2's loads
// stay in flight across the barrier; only tile kt+1's are retired. Invariant: 8 loads
// per thread per tile; at wait, outstanding = 8(kt+1)+8(kt+2) -> vmcnt(8) retires kt+1.
__global__ __launch_bounds__(256, 2)
void k_gemmf(const unsigned short* __restrict__ A0, const unsigned short* __restrict__ A1,
             const unsigned short* __restrict__ P, const float* __restrict__ b2,
             const float* __restrict__ Wl, float* __restrict__ out) {
    constexpr int KT2 = 16;
    __shared__ unsigned short Al[2][128 * 64];     // 32 KB
    __shared__ unsigned short Bl[2][2][4][1024];   // 32 KB

    const int t    = threadIdx.x;
    const int lane = t & 63;
    const int wv   = t >> 6;
    const int wm   = wv >> 1, wn = wv & 1;
    const int wg   = xcd_swz(blockIdx.x, gridDim.x);
    const int ncol = (wg & 3) * 128;
    const int m0   = (wg >> 2) * 128;
    const unsigned short* Pb = P + ncol * 8;
    const int ar0 = t >> 3, ach = t & 7;

    f32x4 acc[4][4];
    #pragma unroll
    for (int m = 0; m < 4; ++m)
        #pragma unroll
        for (int n = 0; n < 4; ++n)
            acc[m][n] = (f32x4){0.f, 0.f, 0.f, 0.f};

    // stage tile kt into buffer b: exactly 8 gl_lds16 per thread, unconditional
    auto stage = [&](int kt, int b) {
        const unsigned short* Ab = (kt < 8 ? A0 : A1) + (size_t)m0 * 512 + (kt & 7) * 64;
        #pragma unroll
        for (int i = 0; i < 4; ++i) {
            int r = i * 32 + ar0;
            gl_lds16(Ab + (size_t)r * 512 + (ach ^ (r & 7)) * 8,
                     &Al[b][i * 2048 + t * 8]);
        }
        #pragma unroll
        for (int h = 0; h < 2; ++h)
            #pragma unroll
            for (int i = 0; i < 2; ++i)
                gl_lds16(Pb + (size_t)(kt * 2 + h) * 16384 + wv * 4096 + lane * 8 + i * 512,
                         &Bl[b][h][wv][lane * 8 + i * 512]);
    };
    auto compute = [&](int b) {
        const int kq = lane >> 4;
        #pragma unroll
        for (int ks = 0; ks < 2; ++ks) {
            bf16x8 af[4], bfr[4];
            #pragma unroll
            for (int m = 0; m < 4; ++m) {
                int r = wm * 64 + m * 16 + (lane & 15);
                int c = ks * 4 + kq;
                af[m] = *(const bf16x8*)&Al[b][r * 64 + (c ^ (r & 7)) * 8];
            }
            #pragma unroll
            for (int n = 0; n < 4; ++n) {
                int c = wn * 64 + n * 16 + (lane & 15);
                bfr[n] = *(const bf16x8*)&Bl[b][ks][kq][c * 8];
            }
            #pragma unroll
            for (int m = 0; m < 4; ++m)
                #pragma unroll
                for (int n = 0; n < 4; ++n)
                    acc[m][n] = __builtin_amdgcn_mfma_f32_16x16x32_bf16(bfr[n], af[m], acc[m][n], 0, 0, 0);
        }
    };

    // prologue: tiles 0,1 in flight; retire tile 0 (vmcnt==8: tile 1 outstanding)
    stage(0, 0);
    stage(1, 1);
    wait_vmcnt8();
    __builtin_amdgcn_s_barrier();

    for (int kt = 0; kt < KT2; ++kt) {
        const int cur = kt & 1;
        compute(cur);                         // all ds_reads feed MFMAs -> lgkm-complete
        __builtin_amdgcn_s_barrier();         // all waves done reading buf[cur]
        if (kt + 2 < KT2) stage(kt + 2, cur); // overwrite freed buffer (8 loads)
        if (kt + 1 < KT2) {
            if (kt + 2 < KT2) wait_vmcnt8();  // retire tile kt+1; kt+2 stays in flight
            else             wait_vmcnt0();   // tail: drain last tile
            __builtin_amdgcn_s_barrier();     // publish buf[cur^1] = tile kt+1
        }
    }

    // fused epilogue: lane holds Z[r][cg..cg+3] per (m,n)
    float s0[4] = {0.f, 0.f, 0.f, 0.f}, s1[4] = {0.f, 0.f, 0.f, 0.f};
    #pragma unroll
    for (int n = 0; n < 4; ++n) {
        int cg = ncol + wn * 64 + n * 16 + (lane >> 4) * 4;
        float4 bb   = *(const float4*)(b2 + cg);
        float4 wl01 = *(const float4*)(Wl + (size_t)cg * 2);
        float4 wl23 = *(const float4*)(Wl + (size_t)cg * 2 + 4);
        float b2v[4] = {bb.x, bb.y, bb.z, bb.w};
        float w0v[4] = {wl01.x, wl01.z, wl23.x, wl23.z};
        float w1v[4] = {wl01.y, wl01.w, wl23.y, wl23.w};
        #pragma unroll
        for (int m = 0; m < 4; ++m)
            #pragma unroll
            for (int j = 0; j < 4; ++j) {
                float z = acc[m][n][j] + b2v[j];
                z = z > 0.f ? z : 0.f;
                s0[m] += z * w0v[j];
                s1[m] += z * w1v[j];
            }
    }
    #pragma unroll
    for (int m = 0; m < 4; ++m) {
        s0[m] += __shfl_xor(s0[m], 16, 64);
        s0[m] += __shfl_xor(s0[m], 32, 64);
        s1[m] += __shfl_xor(s1[m], 16, 64);
        s1[m] += __shfl_xor(s1[m], 32, 64);
    }
    if (lane < 16) {
        #pragma unroll
        for (int m = 0; m < 4; ++m) {
            int r = m0 + wm * 64 + m * 16 + lane;
            if (r < NNODES) {
                unsafeAtomicAdd(&out[2 * (size_t)r],     s0[m]);
                unsafeAtomicAdd(&out[2 * (size_t)r + 1], s1[m]);
            }
        }
    }
}

// ---------------- k_gemmw / k_gemm0: fallback kernels (interleaved U, proven) ---------
__global__ __launch_bounds__(512, 1)
void k_gemmw(const unsigned short* __restrict__ A, const unsigned short* __restrict__ P,
             unsigned short* __restrict__ U, int ooff, int M) {
    constexpr int KT = HID / 32;
    __shared__ unsigned short Al[2][128 * 32];
    __shared__ unsigned short Bl[2][4][HID * 8];

    const int t    = threadIdx.x;
    const int lane = t & 63;
    const int wv   = t >> 6;
    const int wm   = wv >> 2, wn = wv & 3;
    const int m0   = blockIdx.x * 128;

    const int srow = t >> 2;
    const int gch  = ((t & 3) ^ ((srow >> 1) & 3)) * 8;
    const unsigned short* Ab = A + (size_t)(m0 + srow) * 1024 + gch;
    const bool rok = (m0 + srow) < M;
    const unsigned short* Pb = P + (size_t)t * 8;

    f32x4 acc[4][8];
    #pragma unroll
    for (int m = 0; m < 4; ++m)
        #pragma unroll
        for (int n = 0; n < 8; ++n)
            acc[m][n] = (f32x4){0.f, 0.f, 0.f, 0.f};

    if (rok) gl_lds16(Ab, &Al[0][t * 8]);
    #pragma unroll
    for (int q = 0; q < 4; ++q) gl_lds16(Pb + q * 4096, &Bl[0][q][t * 8]);
    __syncthreads();

    int cur = 0;
    for (int kt = 0; kt < KT; ++kt) {
        if (kt + 1 < KT) {
            if (rok) gl_lds16(Ab + (kt + 1) * 32, &Al[cur ^ 1][t * 8]);
            const unsigned short* Pn = Pb + (size_t)(kt + 1) * 16384;
            #pragma unroll
            for (int q = 0; q < 4; ++q)
                gl_lds16(Pn + q * 4096, &Bl[cur ^ 1][q][t * 8]);
        }
        bf16x8 af[4], bfr[8];
        #pragma unroll
        for (int m = 0; m < 4; ++m) {
            int r  = wm * 64 + m * 16 + (lane & 15);
            int kq = lane >> 4;
            af[m] = *(const bf16x8*)&Al[cur][r * 32 + 8 * (kq ^ ((r >> 1) & 3))];
        }
        #pragma unroll
        for (int n = 0; n < 8; ++n) {
            int c = wn * 128 + n * 16 + (lane & 15);
            bfr[n] = *(const bf16x8*)&Bl[cur][lane >> 4][c * 8];
        }
        #pragma unroll
        for (int m = 0; m < 4; ++m)
            #pragma unroll
            for (int n = 0; n < 8; ++n)
                acc[m][n] = __builtin_amdgcn_mfma_f32_16x16x32_bf16(bfr[n], af[m], acc[m][n], 0, 0, 0);
        __syncthreads();
        cur ^= 1;
    }

    #pragma unroll
    for (int m = 0; m < 4; ++m) {
        int r = m0 + wm * 64 + m * 16 + (lane & 15);
        if (r < M) {
            #pragma unroll
            for (int n = 0; n < 8; ++n) {
                int cb = ooff + wn * 128 + n * 16 + (lane >> 4) * 4;
                uint2 pk;
                pk.x = ((unsigned int)f2bf(acc[m][n][1]) << 16) | (unsigned int)f2bf(acc[m][n][0]);
                pk.y = ((unsigned int)f2bf(acc[m][n][3]) << 16) | (unsigned int)f2bf(acc[m][n][2]);
                *(uint2*)&U[(size_t)r * 1024 + cb] = pk;
            }
        }
    }
}

__global__ __launch_bounds__(512, 1)
void k_gemm0(const float* __restrict__ Aptr, const unsigned short* __restrict__ P,
             unsigned short* __restrict__ U, int ooff, int M) {
    constexpr int K  = K1P;
    constexpr int KT = K / 32;
    __shared__ unsigned short Al[128 * 32];
    __shared__ unsigned short Bpl[4][HID * 8];

    const int t    = threadIdx.x;
    const int lane = t & 63;
    const int wv   = t >> 6;
    const int wm   = wv >> 2, wn = wv & 3;
    const int m0   = blockIdx.x * 128;

    f32x4 acc[4][8];
    #pragma unroll
    for (int m = 0; m < 4; ++m)
        #pragma unroll
        for (int n = 0; n < 8; ++n)
            acc[m][n] = (f32x4){0.f, 0.f, 0.f, 0.f};

    const int srow = t >> 2, sch = t & 3;
    const bool rok = (m0 + srow) < M;

    for (int kt = 0; kt < KT; ++kt) {
        const int k0 = kt * 32;
        __syncthreads();
        {
            const int gk = k0 + sch * 8;
            su16x8 av;
            float f[8];
            const float* Ab = Aptr + (size_t)(m0 + srow) * FIN + gk;
            if (rok && gk + 8 <= FIN) {
                f32x4u lo = *(const f32x4u*)Ab;
                f32x4u hi = *(const f32x4u*)(Ab + 4);
                f[0]=lo.x; f[1]=lo.y; f[2]=lo.z; f[3]=lo.w;
                f[4]=hi.x; f[5]=hi.y; f[6]=hi.z; f[7]=hi.w;
            } else {
                #pragma unroll
                for (int j = 0; j < 8; ++j)
                    f[j] = (rok && gk + j < FIN) ? Ab[j] : 0.f;
            }
            #pragma unroll
            for (int j = 0; j < 8; ++j) av[j] = f2bf(f[j]);
            *(su16x8*)&Al[srow * 32 + 8 * (sch ^ ((srow >> 1) & 3))] = av;
        }
        {
            const unsigned short* Pb = P + (size_t)kt * 16384 + t * 8;
            #pragma unroll
            for (int q = 0; q < 4; ++q)
                *(su16x8*)&Bpl[q][t * 8] = *(const su16x8*)(Pb + q * 4096);
        }
        __syncthreads();
        bf16x8 af[4], bfr[8];
        #pragma unroll
        for (int m = 0; m < 4; ++m) {
            int r  = wm * 64 + m * 16 + (lane & 15);
            int kq = lane >> 4;
            af[m] = *(const bf16x8*)&Al[r * 32 + 8 * (kq ^ ((r >> 1) & 3))];
        }
        #pragma unroll
        for (int n = 0; n < 8; ++n) {
            int c = wn * 128 + n * 16 + (lane & 15);
            bfr[n] = *(const bf16x8*)&Bpl[lane >> 4][c * 8];
        }
        #pragma unroll
        for (int m = 0; m < 4; ++m)
            #pragma unroll
            for (int n = 0; n < 8; ++n)
                acc[m][n] = __builtin_amdgcn_mfma_f32_16x16x32_bf16(bfr[n], af[m], acc[m][n], 0, 0, 0);
    }

    #pragma unroll
    for (int m = 0; m < 4; ++m) {
        int r = m0 + wm * 64 + m * 16 + (lane & 15);
        if (r < M) {
            #pragma unroll
            for (int n = 0; n < 8; ++n) {
                int cb = ooff + wn * 128 + n * 16 + (lane >> 4) * 4;
                uint2 pk;
                pk.x = ((unsigned int)f2bf(acc[m][n][1]) << 16) | (unsigned int)f2bf(acc[m][n][0]);
                pk.y = ((unsigned int)f2bf(acc[m][n][3]) << 16) | (unsigned int)f2bf(acc[m][n][2]);
                *(uint2*)&U[(size_t)r * 1024 + cb] = pk;
            }
        }
    }
}

// ------------- fast-path aggr (dense halves, stride 512, precomputed ew) -------------
__global__ void k_aggrh1(unsigned short* __restrict__ dbuf, const unsigned short* __restrict__ gbuf,
                         const int* __restrict__ rowptr, const int* __restrict__ esrc,
                         const float* __restrict__ ew, const float* __restrict__ bias, int M) {
    int wid  = (blockIdx.x * 256 + threadIdx.x) >> 6;
    int lane = threadIdx.x & 63;
    if (wid >= M) return;
    int e0 = rowptr[wid], e1 = rowptr[wid + 1];

    unsigned short* u0 = dbuf + (size_t)wid * 512 + lane * 8;
    uint4 v0 = *(const uint4*)u0;
    unsigned int a0[4] = {v0.x, v0.y, v0.z, v0.w};
    float acc[8], ac2[8];
    #pragma unroll
    for (int i = 0; i < 4; ++i) {
        acc[2 * i]     = bf2f((unsigned short)(a0[i] & 0xffffu));
        acc[2 * i + 1] = bf2f((unsigned short)(a0[i] >> 16));
        ac2[2 * i] = 0.f; ac2[2 * i + 1] = 0.f;
    }
    int e = e0;
    for (; e + 1 < e1; e += 2) {
        int sa = esrc[e], sb = esrc[e + 1];
        float wa = ew[e], wb = ew[e + 1];
        const uint4 va = *(const uint4*)(gbuf + (size_t)sa * 512 + lane * 8);
        const uint4 vb = *(const uint4*)(gbuf + (size_t)sb * 512 + lane * 8);
        unsigned int ua[4] = {va.x, va.y, va.z, va.w};
        unsigned int ub[4] = {vb.x, vb.y, vb.z, vb.w};
        #pragma unroll
        for (int i = 0; i < 4; ++i) {
            acc[2 * i]     += wa * bf2f((unsigned short)(ua[i] & 0xffffu));
            acc[2 * i + 1] += wa * bf2f((unsigned short)(ua[i] >> 16));
            ac2[2 * i]     += wb * bf2f((unsigned short)(ub[i] & 0xffffu));
            ac2[2 * i + 1] += wb * bf2f((unsigned short)(ub[i] >> 16));
        }
    }
    if (e < e1) {
        int sa = esrc[e];
        float wa = ew[e];
        const uint4 va = *(const uint4*)(gbuf + (size_t)sa * 512 + lane * 8);
        unsigned int ua[4] = {va.x, va.y, va.z, va.w};
        #pragma unroll
        for (int i = 0; i < 4; ++i) {
            acc[2 * i]     += wa * bf2f((unsigned short)(ua[i] & 0xffffu));
            acc[2 * i + 1] += wa * bf2f((unsigned short)(ua[i] >> 16));
        }
    }
    float4 c0 = *(const float4*)(bias + lane * 8);
    float4 c1 = *(const float4*)(bias + lane * 8 + 4);
    float bb[8] = {c0.x,c0.y,c0.z,c0.w,c1.x,c1.y,c1.z,c1.w};
    #pragma unroll
    for (int i = 0; i < 8; ++i) {
        float f = acc[i] + ac2[i] + bb[i];
        acc[i] = f > 0.f ? f : 0.f;
    }
    uint4 w4;
    unsigned int* wo = (unsigned int*)&w4;
    #pragma unroll
    for (int i = 0; i < 4; ++i)
        wo[i] = ((unsigned int)f2bf(acc[2 * i + 1]) << 16) | (unsigned int)f2bf(acc[2 * i]);
    *(uint4*)u0 = w4;
}

__global__ void k_aggrh2(unsigned short* __restrict__ dbuf, const unsigned short* __restrict__ gbuf,
                         const int* __restrict__ rowptr, const int* __restrict__ esrc,
                         const float* __restrict__ ew, int M) {
    int wid  = (blockIdx.x * 256 + threadIdx.x) >> 6;
    int lane = threadIdx.x & 63;
    if (wid >= M) return;
    int e0 = rowptr[wid], e1 = rowptr[wid + 1];

    float acc[8] = {0.f,0.f,0.f,0.f,0.f,0.f,0.f,0.f};
    float ac2[8] = {0.f,0.f,0.f,0.f,0.f,0.f,0.f,0.f};
    int e = e0;
    for (; e + 1 < e1; e += 2) {
        int sa = esrc[e], sb = esrc[e + 1];
        float wa = ew[e], wb = ew[e + 1];
        const uint4 va = *(const uint4*)(gbuf + (size_t)sa * 512 + lane * 8);
        const uint4 vb = *(const uint4*)(gbuf + (size_t)sb * 512 + lane * 8);
        unsigned int ua[4] = {va.x, va.y, va.z, va.w};
        unsigned int ub[4] = {vb.x, vb.y, vb.z, vb.w};
        #pragma unroll
        for (int i = 0; i < 4; ++i) {
            acc[2 * i]     += wa * bf2f((unsigned short)(ua[i] & 0xffffu));
            acc[2 * i + 1] += wa * bf2f((unsigned short)(ua[i] >> 16));
            ac2[2 * i]     += wb * bf2f((unsigned short)(ub[i] & 0xffffu));
            ac2[2 * i + 1] += wb * bf2f((unsigned short)(ub[i] >> 16));
        }
    }
    if (e < e1) {
        int sa = esrc[e];
        float wa = ew[e];
        const uint4 va = *(const uint4*)(gbuf + (size_t)sa * 512 + lane * 8);
        unsigned int ua[4] = {va.x, va.y, va.z, va.w};
        #pragma unroll
        for (int i = 0; i < 4; ++i) {
            acc[2 * i]     += wa * bf2f((unsigned short)(ua[i] & 0xffffu));
            acc[2 * i + 1] += wa * bf2f((unsigned short)(ua[i] >> 16));
        }
    }
    uint4 w4;
    unsigned int* wo = (unsigned int*)&w4;
    #pragma unroll
    for (int i = 0; i < 4; ++i)
        wo[i] = ((unsigned int)f2bf(acc[2 * i + 1] + ac2[2 * i + 1]) << 16) |
                 (unsigned int)f2bf(acc[2 * i] + ac2[2 * i]);
    *(uint4*)(dbuf + (size_t)wid * 512 + lane * 8) = w4;
}

// ---------------- fallback aggr (interleaved U, deg-recompute; proven round-12) -------
template<int RELU>
__global__ void k_aggr(unsigned short* U, const int* __restrict__ rowptr,
                       const int* __restrict__ esrc, const int* __restrict__ deg,
                       const float* __restrict__ bias, int M) {
    int wid  = (blockIdx.x * 256 + threadIdx.x) >> 6;
    int lane = threadIdx.x & 63;
    if (wid >= M) return;
    int e0 = rowptr[wid], e1 = rowptr[wid + 1];
    if (RELU == 0 && e0 == e1) return;

    unsigned short* u0 = U + (size_t)wid * 1024 + lane * 8;
    uint4 v0 = *(const uint4*)u0;
    unsigned int a0[4] = {v0.x, v0.y, v0.z, v0.w};
    float acc[8];
    #pragma unroll
    for (int i = 0; i < 4; ++i) {
        acc[2 * i]     = bf2f((unsigned short)(a0[i] & 0xffffu));
        acc[2 * i + 1] = bf2f((unsigned short)(a0[i] >> 16));
    }
    if (e0 < e1) {
        int dd = deg[wid];
        float dr = dd > 0 ? rsqrtf((float)dd) : 0.f;
        for (int e = e0; e < e1; ++e) {
            int s = esrc[e];
            float we = -dr * rsqrtf((float)deg[s]);
            const uint4 v = *(const uint4*)(U + (size_t)s * 1024 + 512 + lane * 8);
            unsigned int uu[4] = {v.x, v.y, v.z, v.w};
            #pragma unroll
            for (int i = 0; i < 4; ++i) {
                acc[2 * i]     += we * bf2f((unsigned short)(uu[i] & 0xffffu));
                acc[2 * i + 1] += we * bf2f((unsigned short)(uu[i] >> 16));
            }
        }
    }
    if (RELU) {
        float4 c0 = *(const float4*)(bias + lane * 8);
        float4 c1 = *(const float4*)(bias + lane * 8 + 4);
        float bb[8] = {c0.x,c0.y,c0.z,c0.w,c1.x,c1.y,c1.z,c1.w};
        #pragma unroll
        for (int i = 0; i < 8; ++i) {
            float f = acc[i] + bb[i];
            acc[i] = f > 0.f ? f : 0.f;
        }
    }
    uint4 w4;
    unsigned int* wo = (unsigned int*)&w4;
    #pragma unroll
    for (int i = 0; i < 4; ++i)
        wo[i] = ((unsigned int)f2bf(acc[2 * i + 1]) << 16) | (unsigned int)f2bf(acc[2 * i]);
    *(uint4*)u0 = w4;
}

// ---------------- fallback final (interleaved U) ----------------
__global__ void k_final(const unsigned short* __restrict__ U, const float* __restrict__ b2,
                        const float* __restrict__ Wl, const float* __restrict__ bl,
                        float* __restrict__ out, int M) {
    int wid  = (blockIdx.x * 256 + threadIdx.x) >> 6;
    int lane = threadIdx.x & 63;
    if (wid >= M) return;
    const uint4 v = *(const uint4*)(U + (size_t)wid * 1024 + lane * 8);
    float4 c0 = *(const float4*)(b2 + lane * 8);
    float4 c1 = *(const float4*)(b2 + lane * 8 + 4);
    float bb[8] = {c0.x,c0.y,c0.z,c0.w,c1.x,c1.y,c1.z,c1.w};
    const float4* Wp = reinterpret_cast<const float4*>(Wl + lane * 16);
    float4 w0 = Wp[0], w1 = Wp[1], w2 = Wp[2], w3 = Wp[3];
    float wv[16] = {w0.x, w0.y, w0.z, w0.w, w1.x, w1.y, w1.z, w1.w,
                    w2.x, w2.y, w2.z, w2.w, w3.x, w3.y, w3.z, w3.w};
    unsigned int uu[4] = {v.x, v.y, v.z, v.w};
    float s0 = 0.f, s1 = 0.f;
    #pragma unroll
    for (int j = 0; j < 4; ++j) {
        float f0 = bf2f((unsigned short)(uu[j] & 0xffffu)) + bb[2 * j];
        float f1 = bf2f((unsigned short)(uu[j] >> 16))     + bb[2 * j + 1];
        f0 = f0 > 0.f ? f0 : 0.f;
        f1 = f1 > 0.f ? f1 : 0.f;
        s0 += f0 * wv[4 * j + 0];
        s1 += f0 * wv[4 * j + 1];
        s0 += f1 * wv[4 * j + 2];
        s1 += f1 * wv[4 * j + 3];
    }
    #pragma unroll
    for (int off = 32; off; off >>= 1) {
        s0 += __shfl_xor(s0, off, 64);
        s1 += __shfl_xor(s1, off, 64);
    }
    if (lane == 0) {
        out[2 * (size_t)wid]     = s0 + bl[0];
        out[2 * (size_t)wid + 1] = s1 + bl[1];
    }
}

extern "C" void kernel_launch(void* const* d_in, const int* in_sizes, int n_in,
                              void* d_out, int out_size, void* d_ws, size_t ws_size,
                              hipStream_t stream) {
    const float* x    = (const float*)d_in[0];
    const int*   ei   = (const int*)d_in[1];
    const float* W1_0 = (const float*)d_in[2];
    const float* W1_1 = (const float*)d_in[3];
    const float* b1   = (const float*)d_in[4];
    const float* W2_0 = (const float*)d_in[5];
    const float* W2_1 = (const float*)d_in[6];
    const float* b2   = (const float*)d_in[7];
    const float* Wl   = (const float*)d_in[8];
    const float* bl   = (const float*)d_in[9];
    const int* src = ei;
    const int* dst = ei + NEDGES;
    float* out = (float*)d_out;

    char* ws = (char*)d_ws;
    size_t off = 0;
    auto alloc = [&](size_t bytes) -> void* {
        void* p = ws + off;
        off += (bytes + 255) & ~(size_t)255;
        return p;
    };
    int*            deg    = (int*)alloc((size_t)NNODES * 4);
    int*            cnt    = (int*)alloc((size_t)NNODES * 4);
    int*            rowptr = (int*)alloc((size_t)(NNODES + 1) * 4);
    int*            btot   = (int*)alloc((size_t)NB * 4);
    unsigned short* P1     = (unsigned short*)alloc((size_t)2 * K1P * HID * 2);
    unsigned short* P2     = (unsigned short*)alloc((size_t)2 * HID * HID * 2);
    unsigned short* Hbuf   = (unsigned short*)alloc((size_t)MPAD * 1024 * 2);
    unsigned short* H0 = Hbuf;                        // fast path: dense [MPAD x 512]
    unsigned short* H1 = Hbuf + (size_t)MPAD * 512;   // fast path: dense [MPAD x 512]
    unsigned short* U  = Hbuf;                        // fallback: interleaved [MPAD x 1024]

    bool esrc_ws = (off + (size_t)NEDGES * 8 <= ws_size);
    int*   esrc = esrc_ws ? (int*)alloc((size_t)NEDGES * 4)   : (int*)d_out;
    float* ew   = esrc_ws ? (float*)alloc((size_t)NEDGES * 4) : nullptr;
    bool have_xb = (off + (size_t)MPAD * K1P * 2 <= ws_size);
    unsigned short* xb = have_xb ? (unsigned short*)alloc((size_t)MPAD * K1P * 2) : nullptr;

    hipMemsetAsync(deg, 0, (size_t)NNODES * 4, stream);
    hipMemsetAsync(cnt, 0, (size_t)NNODES * 4, stream);

    // CSR build + degrees + edge weights (+ out=bl init on fast path; E == 2*NNODES)
    k_deg    <<<(NEDGES + 255) / 256, 256, 0, stream>>>(src, dst, deg, cnt, NEDGES);
    k_scan1  <<<NB, 256, 0, stream>>>(cnt, btot, NNODES);
    k_scan2  <<<1, 1024, 0, stream>>>(btot, NB);
    k_scan3  <<<NB, 256, 0, stream>>>(cnt, btot, rowptr, NNODES, NEDGES);
    k_scatter<<<(NEDGES + 255) / 256, 256, 0, stream>>>(src, dst, rowptr, cnt, deg, esrc,
                                                        ew, esrc_ws ? out : nullptr, bl, NEDGES);

    // weight panels
    k_buildP1<<<(2 * K1P * HID + 255) / 256, 256, 0, stream>>>(W1_0, W1_1, P1);
    if (esrc_ws) {
        k_buildP2cat<<<(1024 * HID + 255) / 256, 256, 0, stream>>>(W2_0, W2_1, P2);
    } else {
        const int pg2 = (HID * HID + 255) / 256;
        k_buildP<<<pg2, 256, 0, stream>>>(W2_0, P2, HID, HID);
        k_buildP<<<pg2, 256, 0, stream>>>(W2_1, P2 + (size_t)HID * HID, HID, HID);
    }

    const int nblk = MPAD / 128;  // 1563

    if (esrc_ws && have_xb) {
        // fast path: dense halves H0 (panel-0 result -> h1) and H1 (panel-1 -> prop)
        k_xcvt<<<(int)(((long)NNODES * K1P / 8 + 255) / 256), 256, 0, stream>>>(x, xb);
        k_gemms<K1P, K1P, 8><<<8 * nblk, 256, 0, stream>>>(xb, P1, H0, H1, 512, 512, 0, 0);
        k_aggrh1<<<NNODES / 4, 256, 0, stream>>>(H0, H1, rowptr, esrc, ew, b1, NNODES);
        k_aggrh2<<<NNODES / 4, 256, 0, stream>>>(H1, H0, rowptr, esrc, ew, NNODES);
        k_gemmf<<<4 * nblk, 256, 0, stream>>>(H0, H1, P2, b2, Wl, out);
    } else {
        // fallback: interleaved-U path (round-12 proven)
        if (have_xb) {
            k_xcvt<<<(int)(((long)NNODES * K1P / 8 + 255) / 256), 256, 0, stream>>>(x, xb);
            k_gemms<K1P, K1P, 8><<<8 * nblk, 256, 0, stream>>>(xb, P1, U, U, 1024, 1024, 0, 512);
        } else {
            k_gemm0<<<nblk, 512, 0, stream>>>(x, P1, U, 0, NNODES);
            k_gemm0<<<nblk, 512, 0, stream>>>(x, P1 + (size_t)K1P * HID, U, 512, NNODES);
        }
        k_aggr<1><<<NNODES / 4, 256, 0, stream>>>(U, rowptr, esrc, deg, b1, NNODES);
        k_gemms<HID, 1024, 4><<<4 * nblk, 256, 0, stream>>>(U, P2 + (size_t)HID * HID,
                                                            U, U, 1024, 1024, 512, 512);
        k_gemmw<<<nblk, 512, 0, stream>>>(U, P2, U, 0, NNODES);
        k_aggr<0><<<NNODES / 4, 256, 0, stream>>>(U, rowptr, esrc, deg, nullptr, NNODES);
        k_final<<<NNODES / 4, 256, 0, stream>>>(U, b2, Wl, bl, out, NNODES);
    }
}

// Round 17
// 773.465 us; speedup vs baseline: 1.0751x; 1.0751x over previous
//
#include <hip/hip_runtime.h>

#define NNODES 200000
#define MPAD   200064   // NNODES rounded up to 128
#define NEDGES 400000
#define FIN    165
#define K1P    192      // FIN padded to 6 x 32
#define HID    512
#define NB     ((NNODES + 255) / 256)   // 782 scan blocks

typedef __bf16 bf16_t;
typedef __bf16 bf16x8 __attribute__((ext_vector_type(8)));
typedef float  f32x4  __attribute__((ext_vector_type(4)));
typedef unsigned short su16x8 __attribute__((ext_vector_type(8)));
typedef float f32x4u __attribute__((ext_vector_type(4), aligned(4)));

static __device__ __forceinline__ float bf2f(unsigned short u) {
    unsigned int x = ((unsigned int)u) << 16;
    return __builtin_bit_cast(float, x);
}
static __device__ __forceinline__ unsigned short f2bf(float f) {
    bf16_t h = (bf16_t)f;  // RNE
    return __builtin_bit_cast(unsigned short, h);
}
// async global->LDS, 16B per lane (dest = wave-uniform base + lane*16)
static __device__ __forceinline__ void gl_lds16(const void* g, void* l) {
    __builtin_amdgcn_global_load_lds(
        (const __attribute__((address_space(1))) unsigned int*)g,
        (__attribute__((address_space(3))) unsigned int*)l, 16, 0, 0);
}
// m204 bijective XCD-chunked swizzle
static __device__ __forceinline__ int xcd_swz(int i, int nb) {
    int q = nb >> 3, r = nb & 7;
    int xcd = i & 7, seq = i >> 3;
    return (xcd < r ? xcd * (q + 1) : r * (q + 1) + (xcd - r) * q) + seq;
}

// ---------------- degree histograms ----------------
__global__ void k_deg(const int* __restrict__ src, const int* __restrict__ dst,
                      int* __restrict__ deg, int* __restrict__ cnt, int E) {
    int e = blockIdx.x * 256 + threadIdx.x;
    if (e < E) {
        atomicAdd(&deg[src[e]], 1);
        atomicAdd(&cnt[dst[e]], 1);
    }
}

// ---------------- CSR build: 2-level exclusive scan ----------------
__global__ void k_scan1(int* __restrict__ cnt, int* __restrict__ btot, int n) {
    __shared__ int s[256];
    int i = blockIdx.x * 256 + threadIdx.x;
    int v = (i < n) ? cnt[i] : 0;
    s[threadIdx.x] = v;
    __syncthreads();
    #pragma unroll
    for (int off = 1; off < 256; off <<= 1) {
        int t = (threadIdx.x >= off) ? s[threadIdx.x - off] : 0;
        __syncthreads();
        s[threadIdx.x] += t;
        __syncthreads();
    }
    if (i < n) cnt[i] = s[threadIdx.x] - v;
    if (threadIdx.x == 255) btot[blockIdx.x] = s[255];
}

__global__ void k_scan2(int* __restrict__ btot, int nb) {
    __shared__ int s[1024];
    int i = threadIdx.x;
    int v = (i < nb) ? btot[i] : 0;
    s[i] = v;
    __syncthreads();
    #pragma unroll
    for (int off = 1; off < 1024; off <<= 1) {
        int t = (i >= off) ? s[i - off] : 0;
        __syncthreads();
        s[i] += t;
        __syncthreads();
    }
    if (i < nb) btot[i] = s[i] - v;
}

__global__ void k_scan3(int* __restrict__ cnt, const int* __restrict__ btot,
                        int* __restrict__ rowptr, int n, int E) {
    int i = blockIdx.x * 256 + threadIdx.x;
    if (i < n) {
        rowptr[i] = cnt[i] + btot[blockIdx.x];
        cnt[i] = 0;
    }
    if (i == 0) rowptr[n] = E;
}

// scatter edge -> CSR slot; precompute edge weight; optionally init out=bl (E==2*NNODES)
__global__ void k_scatter(const int* __restrict__ src, const int* __restrict__ dst,
                          const int* __restrict__ rowptr, int* __restrict__ cur,
                          const int* __restrict__ deg, int* __restrict__ esrc,
                          float* __restrict__ ew, float* __restrict__ outinit,
                          const float* __restrict__ bl, int E) {
    int e = blockIdx.x * 256 + threadIdx.x;
    if (e < E) {
        int s = src[e], d = dst[e];
        int pos = rowptr[d] + atomicAdd(&cur[d], 1);
        esrc[pos] = s;
        if (ew) {
            int da = deg[s], db = deg[d];
            float fa = da > 0 ? rsqrtf((float)da) : 0.f;
            float fb = db > 0 ? rsqrtf((float)db) : 0.f;
            ew[pos] = -fa * fb;
        }
        if (outinit) outinit[e] = bl[e & 1];
    }
}

// ---------------- build BOTH k-tiled bf16 B panels of layer 1 in one launch ----------
__global__ void k_buildP1(const float* __restrict__ W0, const float* __restrict__ W1,
                          unsigned short* __restrict__ P) {
    int idx = blockIdx.x * 256 + threadIdx.x;   // 2 * K1P * HID
    if (idx >= 2 * K1P * HID) return;
    int panel = idx / (K1P * HID);
    int rem   = idx - panel * (K1P * HID);
    int j  = rem & 7;
    int n  = (rem >> 3) & 511;
    int q  = (rem >> 12) & 3;
    int kt = rem >> 14;
    int k  = kt * 32 + q * 8 + j;
    const float* W = panel ? W1 : W0;
    P[idx] = (k < FIN) ? f2bf(W[(size_t)k * HID + n]) : (unsigned short)0;
}

// fallback single-panel builder (kp x 512)
__global__ void k_buildP(const float* __restrict__ W, unsigned short* __restrict__ P,
                         int kp, int kfull) {
    int idx = blockIdx.x * 256 + threadIdx.x;
    if (idx >= kp * HID) return;
    int j  = idx & 7;
    int n  = (idx >> 3) & 511;
    int q  = (idx >> 12) & 3;
    int kt = idx >> 14;
    int k  = kt * 32 + q * 8 + j;
    P[idx] = (k < kfull) ? f2bf(W[(size_t)k * HID + n]) : (unsigned short)0;
}

// concat panel for layer 2: K=1024, k<512 -> W2_0[k][n], else W2_1[k-512][n]
__global__ void k_buildP2cat(const float* __restrict__ W0, const float* __restrict__ W1,
                             unsigned short* __restrict__ P) {
    int idx = blockIdx.x * 256 + threadIdx.x;   // 1024*512 elems
    if (idx >= 1024 * HID) return;
    int j  = idx & 7;
    int n  = (idx >> 3) & 511;
    int q  = (idx >> 12) & 3;
    int kt = idx >> 14;
    int k  = kt * 32 + q * 8 + j;
    float v = (k < HID) ? W0[(size_t)k * HID + n] : W1[(size_t)(k - HID) * HID + n];
    P[idx] = f2bf(v);
}

// ---------------- x -> bf16 padded [MPAD x 192] ----------------
__global__ void k_xcvt(const float* __restrict__ x, unsigned short* __restrict__ xb) {
    long i = ((long)blockIdx.x * 256 + threadIdx.x) * 8;
    if (i >= (long)NNODES * K1P) return;
    int row = (int)(i / K1P), k = (int)(i % K1P);
    const float* xr = x + (size_t)row * FIN;
    __align__(16) unsigned short v[8];
    #pragma unroll
    for (int j = 0; j < 8; ++j)
        v[j] = (k + j < FIN) ? f2bf(xr[k + j]) : (unsigned short)0;
    *(su16x8*)&xb[i] = *(su16x8*)v;
}

// ======== BK=64 core (round-14 proven): one stage+barrier pair per 32 MFMA ========

// ---------------- k_gemms: 128x128-tile GEMM, 1D XCD-swizzled grid, BK=64 -------------
template<int K, int LDA, int NCMB>
__global__ __launch_bounds__(256, 4)
void k_gemms(const unsigned short* __restrict__ A, const unsigned short* __restrict__ P,
             unsigned short* __restrict__ D0, unsigned short* __restrict__ D1,
             int os0, int os1, int ob0, int ob1) {
    constexpr int KT2 = K / 64;
    __shared__ unsigned short Al[128 * 64];     // 16 KB
    __shared__ unsigned short Bl[2][4][1024];   // 16 KB

    const int t    = threadIdx.x;
    const int lane = t & 63;
    const int wv   = t >> 6;
    const int wm   = wv >> 1, wn = wv & 1;
    const int wg   = xcd_swz(blockIdx.x, gridDim.x);
    const int combo = wg & (NCMB - 1);
    const int sel  = combo >> 2;
    const int ncol = (combo & 3) * 128;
    const int m0   = (wg / NCMB) * 128;
    const unsigned short* Pb = P + (size_t)sel * K * 512 + ncol * 8;
    unsigned short* D = sel ? D1 : D0;
    const int os = sel ? os1 : os0;
    const int oc = (sel ? ob1 : ob0) + ncol;

    const unsigned short* Ab = A + (size_t)m0 * LDA;
    const int ar0 = t >> 3;          // row within each 32-row band
    const int ach = t & 7;           // phys chunk

    f32x4 acc[4][4];
    #pragma unroll
    for (int m = 0; m < 4; ++m)
        #pragma unroll
        for (int n = 0; n < 4; ++n)
            acc[m][n] = (f32x4){0.f, 0.f, 0.f, 0.f};

    for (int kt = 0; kt < KT2; ++kt) {
        __syncthreads();
        #pragma unroll
        for (int i = 0; i < 4; ++i) {   // stage A: row = i*32 + ar0, src chunk = ach^(row&7)
            int r = i * 32 + ar0;
            gl_lds16(Ab + (size_t)r * LDA + kt * 64 + (ach ^ (r & 7)) * 8,
                     &Al[i * 2048 + t * 8]);
        }
        #pragma unroll
        for (int h = 0; h < 2; ++h)
            #pragma unroll
            for (int i = 0; i < 2; ++i)
                gl_lds16(Pb + (size_t)(kt * 2 + h) * 16384 + wv * 4096 + lane * 8 + i * 512,
                         &Bl[h][wv][lane * 8 + i * 512]);
        __syncthreads();

        const int kq = lane >> 4;
        #pragma unroll
        for (int ks = 0; ks < 2; ++ks) {
            bf16x8 af[4], bfr[4];
            #pragma unroll
            for (int m = 0; m < 4; ++m) {
                int r = wm * 64 + m * 16 + (lane & 15);
                int c = ks * 4 + kq;
                af[m] = *(const bf16x8*)&Al[r * 64 + (c ^ (r & 7)) * 8];
            }
            #pragma unroll
            for (int n = 0; n < 4; ++n) {
                int c = wn * 64 + n * 16 + (lane & 15);
                bfr[n] = *(const bf16x8*)&Bl[ks][kq][c * 8];
            }
            #pragma unroll
            for (int m = 0; m < 4; ++m)
                #pragma unroll
                for (int n = 0; n < 4; ++n)
                    acc[m][n] = __builtin_amdgcn_mfma_f32_16x16x32_bf16(bfr[n], af[m], acc[m][n], 0, 0, 0);
        }
    }

    #pragma unroll
    for (int m = 0; m < 4; ++m) {
        int r = m0 + wm * 64 + m * 16 + (lane & 15);
        #pragma unroll
        for (int n = 0; n < 4; ++n) {
            int cb = oc + wn * 64 + n * 16 + (lane >> 4) * 4;
            uint2 pk;
            pk.x = ((unsigned int)f2bf(acc[m][n][1]) << 16) | (unsigned int)f2bf(acc[m][n][0]);
            pk.y = ((unsigned int)f2bf(acc[m][n][3]) << 16) | (unsigned int)f2bf(acc[m][n][2]);
            *(uint2*)&D[(size_t)r * os + cb] = pk;
        }
    }
}

// ---------------- k_gemmf: K=1024 concat GEMM (BK=64, A = [H0|H1] dense halves) -------
__global__ __launch_bounds__(256, 4)
void k_gemmf(const unsigned short* __restrict__ A0, const unsigned short* __restrict__ A1,
             const unsigned short* __restrict__ P, const float* __restrict__ b2,
             const float* __restrict__ Wl, float* __restrict__ out) {
    constexpr int KT2 = 16;
    __shared__ unsigned short Al[128 * 64];
    __shared__ unsigned short Bl[2][4][1024];

    const int t    = threadIdx.x;
    const int lane = t & 63;
    const int wv   = t >> 6;
    const int wm   = wv >> 1, wn = wv & 1;
    const int wg   = xcd_swz(blockIdx.x, gridDim.x);
    const int ncol = (wg & 3) * 128;
    const int m0   = (wg >> 2) * 128;
    const unsigned short* Pb = P + ncol * 8;
    const int ar0 = t >> 3, ach = t & 7;

    f32x4 acc[4][4];
    #pragma unroll
    for (int m = 0; m < 4; ++m)
        #pragma unroll
        for (int n = 0; n < 4; ++n)
            acc[m][n] = (f32x4){0.f, 0.f, 0.f, 0.f};

    for (int kt = 0; kt < KT2; ++kt) {
        const unsigned short* Ab = (kt < 8 ? A0 : A1) + (size_t)m0 * 512 + (kt & 7) * 64;
        __syncthreads();
        #pragma unroll
        for (int i = 0; i < 4; ++i) {
            int r = i * 32 + ar0;
            gl_lds16(Ab + (size_t)r * 512 + (ach ^ (r & 7)) * 8,
                     &Al[i * 2048 + t * 8]);
        }
        #pragma unroll
        for (int h = 0; h < 2; ++h)
            #pragma unroll
            for (int i = 0; i < 2; ++i)
                gl_lds16(Pb + (size_t)(kt * 2 + h) * 16384 + wv * 4096 + lane * 8 + i * 512,
                         &Bl[h][wv][lane * 8 + i * 512]);
        __syncthreads();

        const int kq = lane >> 4;
        #pragma unroll
        for (int ks = 0; ks < 2; ++ks) {
            bf16x8 af[4], bfr[4];
            #pragma unroll
            for (int m = 0; m < 4; ++m) {
                int r = wm * 64 + m * 16 + (lane & 15);
                int c = ks * 4 + kq;
                af[m] = *(const bf16x8*)&Al[r * 64 + (c ^ (r & 7)) * 8];
            }
            #pragma unroll
            for (int n = 0; n < 4; ++n) {
                int c = wn * 64 + n * 16 + (lane & 15);
                bfr[n] = *(const bf16x8*)&Bl[ks][kq][c * 8];
            }
            #pragma unroll
            for (int m = 0; m < 4; ++m)
                #pragma unroll
                for (int n = 0; n < 4; ++n)
                    acc[m][n] = __builtin_amdgcn_mfma_f32_16x16x32_bf16(bfr[n], af[m], acc[m][n], 0, 0, 0);
        }
    }

    // fused epilogue: lane holds Z[r][cg..cg+3] per (m,n)
    float s0[4] = {0.f, 0.f, 0.f, 0.f}, s1[4] = {0.f, 0.f, 0.f, 0.f};
    #pragma unroll
    for (int n = 0; n < 4; ++n) {
        int cg = ncol + wn * 64 + n * 16 + (lane >> 4) * 4;
        float4 bb   = *(const float4*)(b2 + cg);
        float4 wl01 = *(const float4*)(Wl + (size_t)cg * 2);
        float4 wl23 = *(const float4*)(Wl + (size_t)cg * 2 + 4);
        float b2v[4] = {bb.x, bb.y, bb.z, bb.w};
        float w0v[4] = {wl01.x, wl01.z, wl23.x, wl23.z};
        float w1v[4] = {wl01.y, wl01.w, wl23.y, wl23.w};
        #pragma unroll
        for (int m = 0; m < 4; ++m)
            #pragma unroll
            for (int j = 0; j < 4; ++j) {
                float z = acc[m][n][j] + b2v[j];
                z = z > 0.f ? z : 0.f;
                s0[m] += z * w0v[j];
                s1[m] += z * w1v[j];
            }
    }
    #pragma unroll
    for (int m = 0; m < 4; ++m) {
        s0[m] += __shfl_xor(s0[m], 16, 64);
        s0[m] += __shfl_xor(s0[m], 32, 64);
        s1[m] += __shfl_xor(s1[m], 16, 64);
        s1[m] += __shfl_xor(s1[m], 32, 64);
    }
    if (lane < 16) {
        #pragma unroll
        for (int m = 0; m < 4; ++m) {
            int r = m0 + wm * 64 + m * 16 + lane;
            if (r < NNODES) {
                unsafeAtomicAdd(&out[2 * (size_t)r],     s0[m]);
                unsafeAtomicAdd(&out[2 * (size_t)r + 1], s1[m]);
            }
        }
    }
}

// ---------------- k_gemmw / k_gemm0: fallback kernels (interleaved U, proven) ---------
__global__ __launch_bounds__(512, 1)
void k_gemmw(const unsigned short* __restrict__ A, const unsigned short* __restrict__ P,
             unsigned short* __restrict__ U, int ooff, int M) {
    constexpr int KT = HID / 32;
    __shared__ unsigned short Al[2][128 * 32];
    __shared__ unsigned short Bl[2][4][HID * 8];

    const int t    = threadIdx.x;
    const int lane = t & 63;
    const int wv   = t >> 6;
    const int wm   = wv >> 2, wn = wv & 3;
    const int m0   = blockIdx.x * 128;

    const int srow = t >> 2;
    const int gch  = ((t & 3) ^ ((srow >> 1) & 3)) * 8;
    const unsigned short* Ab = A + (size_t)(m0 + srow) * 1024 + gch;
    const bool rok = (m0 + srow) < M;
    const unsigned short* Pb = P + (size_t)t * 8;

    f32x4 acc[4][8];
    #pragma unroll
    for (int m = 0; m < 4; ++m)
        #pragma unroll
        for (int n = 0; n < 8; ++n)
            acc[m][n] = (f32x4){0.f, 0.f, 0.f, 0.f};

    if (rok) gl_lds16(Ab, &Al[0][t * 8]);
    #pragma unroll
    for (int q = 0; q < 4; ++q) gl_lds16(Pb + q * 4096, &Bl[0][q][t * 8]);
    __syncthreads();

    int cur = 0;
    for (int kt = 0; kt < KT; ++kt) {
        if (kt + 1 < KT) {
            if (rok) gl_lds16(Ab + (kt + 1) * 32, &Al[cur ^ 1][t * 8]);
            const unsigned short* Pn = Pb + (size_t)(kt + 1) * 16384;
            #pragma unroll
            for (int q = 0; q < 4; ++q)
                gl_lds16(Pn + q * 4096, &Bl[cur ^ 1][q][t * 8]);
        }
        bf16x8 af[4], bfr[8];
        #pragma unroll
        for (int m = 0; m < 4; ++m) {
            int r  = wm * 64 + m * 16 + (lane & 15);
            int kq = lane >> 4;
            af[m] = *(const bf16x8*)&Al[cur][r * 32 + 8 * (kq ^ ((r >> 1) & 3))];
        }
        #pragma unroll
        for (int n = 0; n < 8; ++n) {
            int c = wn * 128 + n * 16 + (lane & 15);
            bfr[n] = *(const bf16x8*)&Bl[cur][lane >> 4][c * 8];
        }
        #pragma unroll
        for (int m = 0; m < 4; ++m)
            #pragma unroll
            for (int n = 0; n < 8; ++n)
                acc[m][n] = __builtin_amdgcn_mfma_f32_16x16x32_bf16(bfr[n], af[m], acc[m][n], 0, 0, 0);
        __syncthreads();
        cur ^= 1;
    }

    #pragma unroll
    for (int m = 0; m < 4; ++m) {
        int r = m0 + wm * 64 + m * 16 + (lane & 15);
        if (r < M) {
            #pragma unroll
            for (int n = 0; n < 8; ++n) {
                int cb = ooff + wn * 128 + n * 16 + (lane >> 4) * 4;
                uint2 pk;
                pk.x = ((unsigned int)f2bf(acc[m][n][1]) << 16) | (unsigned int)f2bf(acc[m][n][0]);
                pk.y = ((unsigned int)f2bf(acc[m][n][3]) << 16) | (unsigned int)f2bf(acc[m][n][2]);
                *(uint2*)&U[(size_t)r * 1024 + cb] = pk;
            }
        }
    }
}

__global__ __launch_bounds__(512, 1)
void k_gemm0(const float* __restrict__ Aptr, const unsigned short* __restrict__ P,
             unsigned short* __restrict__ U, int ooff, int M) {
    constexpr int K  = K1P;
    constexpr int KT = K / 32;
    __shared__ unsigned short Al[128 * 32];
    __shared__ unsigned short Bpl[4][HID * 8];

    const int t    = threadIdx.x;
    const int lane = t & 63;
    const int wv   = t >> 6;
    const int wm   = wv >> 2, wn = wv & 3;
    const int m0   = blockIdx.x * 128;

    f32x4 acc[4][8];
    #pragma unroll
    for (int m = 0; m < 4; ++m)
        #pragma unroll
        for (int n = 0; n < 8; ++n)
            acc[m][n] = (f32x4){0.f, 0.f, 0.f, 0.f};

    const int srow = t >> 2, sch = t & 3;
    const bool rok = (m0 + srow) < M;

    for (int kt = 0; kt < KT; ++kt) {
        const int k0 = kt * 32;
        __syncthreads();
        {
            const int gk = k0 + sch * 8;
            su16x8 av;
            float f[8];
            const float* Ab = Aptr + (size_t)(m0 + srow) * FIN + gk;
            if (rok && gk + 8 <= FIN) {
                f32x4u lo = *(const f32x4u*)Ab;
                f32x4u hi = *(const f32x4u*)(Ab + 4);
                f[0]=lo.x; f[1]=lo.y; f[2]=lo.z; f[3]=lo.w;
                f[4]=hi.x; f[5]=hi.y; f[6]=hi.z; f[7]=hi.w;
            } else {
                #pragma unroll
                for (int j = 0; j < 8; ++j)
                    f[j] = (rok && gk + j < FIN) ? Ab[j] : 0.f;
            }
            #pragma unroll
            for (int j = 0; j < 8; ++j) av[j] = f2bf(f[j]);
            *(su16x8*)&Al[srow * 32 + 8 * (sch ^ ((srow >> 1) & 3))] = av;
        }
        {
            const unsigned short* Pb = P + (size_t)kt * 16384 + t * 8;
            #pragma unroll
            for (int q = 0; q < 4; ++q)
                *(su16x8*)&Bpl[q][t * 8] = *(const su16x8*)(Pb + q * 4096);
        }
        __syncthreads();
        bf16x8 af[4], bfr[8];
        #pragma unroll
        for (int m = 0; m < 4; ++m) {
            int r  = wm * 64 + m * 16 + (lane & 15);
            int kq = lane >> 4;
            af[m] = *(const bf16x8*)&Al[r * 32 + 8 * (kq ^ ((r >> 1) & 3))];
        }
        #pragma unroll
        for (int n = 0; n < 8; ++n) {
            int c = wn * 128 + n * 16 + (lane & 15);
            bfr[n] = *(const bf16x8*)&Bpl[lane >> 4][c * 8];
        }
        #pragma unroll
        for (int m = 0; m < 4; ++m)
            #pragma unroll
            for (int n = 0; n < 8; ++n)
                acc[m][n] = __builtin_amdgcn_mfma_f32_16x16x32_bf16(bfr[n], af[m], acc[m][n], 0, 0, 0);
    }

    #pragma unroll
    for (int m = 0; m < 4; ++m) {
        int r = m0 + wm * 64 + m * 16 + (lane & 15);
        if (r < M) {
            #pragma unroll
            for (int n = 0; n < 8; ++n) {
                int cb = ooff + wn * 128 + n * 16 + (lane >> 4) * 4;
                uint2 pk;
                pk.x = ((unsigned int)f2bf(acc[m][n][1]) << 16) | (unsigned int)f2bf(acc[m][n][0]);
                pk.y = ((unsigned int)f2bf(acc[m][n][3]) << 16) | (unsigned int)f2bf(acc[m][n][2]);
                *(uint2*)&U[(size_t)r * 1024 + cb] = pk;
            }
        }
    }
}

// ------------- fast-path aggr (dense halves, stride 512, precomputed ew) -------------
__global__ void k_aggrh1(unsigned short* __restrict__ dbuf, const unsigned short* __restrict__ gbuf,
                         const int* __restrict__ rowptr, const int* __restrict__ esrc,
                         const float* __restrict__ ew, const float* __restrict__ bias, int M) {
    int wid  = (blockIdx.x * 256 + threadIdx.x) >> 6;
    int lane = threadIdx.x & 63;
    if (wid >= M) return;
    int e0 = rowptr[wid], e1 = rowptr[wid + 1];

    unsigned short* u0 = dbuf + (size_t)wid * 512 + lane * 8;
    uint4 v0 = *(const uint4*)u0;
    unsigned int a0[4] = {v0.x, v0.y, v0.z, v0.w};
    float acc[8], ac2[8];
    #pragma unroll
    for (int i = 0; i < 4; ++i) {
        acc[2 * i]     = bf2f((unsigned short)(a0[i] & 0xffffu));
        acc[2 * i + 1] = bf2f((unsigned short)(a0[i] >> 16));
        ac2[2 * i] = 0.f; ac2[2 * i + 1] = 0.f;
    }
    int e = e0;
    for (; e + 1 < e1; e += 2) {
        int sa = esrc[e], sb = esrc[e + 1];
        float wa = ew[e], wb = ew[e + 1];
        const uint4 va = *(const uint4*)(gbuf + (size_t)sa * 512 + lane * 8);
        const uint4 vb = *(const uint4*)(gbuf + (size_t)sb * 512 + lane * 8);
        unsigned int ua[4] = {va.x, va.y, va.z, va.w};
        unsigned int ub[4] = {vb.x, vb.y, vb.z, vb.w};
        #pragma unroll
        for (int i = 0; i < 4; ++i) {
            acc[2 * i]     += wa * bf2f((unsigned short)(ua[i] & 0xffffu));
            acc[2 * i + 1] += wa * bf2f((unsigned short)(ua[i] >> 16));
            ac2[2 * i]     += wb * bf2f((unsigned short)(ub[i] & 0xffffu));
            ac2[2 * i + 1] += wb * bf2f((unsigned short)(ub[i] >> 16));
        }
    }
    if (e < e1) {
        int sa = esrc[e];
        float wa = ew[e];
        const uint4 va = *(const uint4*)(gbuf + (size_t)sa * 512 + lane * 8);
        unsigned int ua[4] = {va.x, va.y, va.z, va.w};
        #pragma unroll
        for (int i = 0; i < 4; ++i) {
            acc[2 * i]     += wa * bf2f((unsigned short)(ua[i] & 0xffffu));
            acc[2 * i + 1] += wa * bf2f((unsigned short)(ua[i] >> 16));
        }
    }
    float4 c0 = *(const float4*)(bias + lane * 8);
    float4 c1 = *(const float4*)(bias + lane * 8 + 4);
    float bb[8] = {c0.x,c0.y,c0.z,c0.w,c1.x,c1.y,c1.z,c1.w};
    #pragma unroll
    for (int i = 0; i < 8; ++i) {
        float f = acc[i] + ac2[i] + bb[i];
        acc[i] = f > 0.f ? f : 0.f;
    }
    uint4 w4;
    unsigned int* wo = (unsigned int*)&w4;
    #pragma unroll
    for (int i = 0; i < 4; ++i)
        wo[i] = ((unsigned int)f2bf(acc[2 * i + 1]) << 16) | (unsigned int)f2bf(acc[2 * i]);
    *(uint4*)u0 = w4;
}

__global__ void k_aggrh2(unsigned short* __restrict__ dbuf, const unsigned short* __restrict__ gbuf,
                         const int* __restrict__ rowptr, const int* __restrict__ esrc,
                         const float* __restrict__ ew, int M) {
    int wid  = (blockIdx.x * 256 + threadIdx.x) >> 6;
    int lane = threadIdx.x & 63;
    if (wid >= M) return;
    int e0 = rowptr[wid], e1 = rowptr[wid + 1];

    float acc[8] = {0.f,0.f,0.f,0.f,0.f,0.f,0.f,0.f};
    float ac2[8] = {0.f,0.f,0.f,0.f,0.f,0.f,0.f,0.f};
    int e = e0;
    for (; e + 1 < e1; e += 2) {
        int sa = esrc[e], sb = esrc[e + 1];
        float wa = ew[e], wb = ew[e + 1];
        const uint4 va = *(const uint4*)(gbuf + (size_t)sa * 512 + lane * 8);
        const uint4 vb = *(const uint4*)(gbuf + (size_t)sb * 512 + lane * 8);
        unsigned int ua[4] = {va.x, va.y, va.z, va.w};
        unsigned int ub[4] = {vb.x, vb.y, vb.z, vb.w};
        #pragma unroll
        for (int i = 0; i < 4; ++i) {
            acc[2 * i]     += wa * bf2f((unsigned short)(ua[i] & 0xffffu));
            acc[2 * i + 1] += wa * bf2f((unsigned short)(ua[i] >> 16));
            ac2[2 * i]     += wb * bf2f((unsigned short)(ub[i] & 0xffffu));
            ac2[2 * i + 1] += wb * bf2f((unsigned short)(ub[i] >> 16));
        }
    }
    if (e < e1) {
        int sa = esrc[e];
        float wa = ew[e];
        const uint4 va = *(const uint4*)(gbuf + (size_t)sa * 512 + lane * 8);
        unsigned int ua[4] = {va.x, va.y, va.z, va.w};
        #pragma unroll
        for (int i = 0; i < 4; ++i) {
            acc[2 * i]     += wa * bf2f((unsigned short)(ua[i] & 0xffffu));
            acc[2 * i + 1] += wa * bf2f((unsigned short)(ua[i] >> 16));
        }
    }
    uint4 w4;
    unsigned int* wo = (unsigned int*)&w4;
    #pragma unroll
    for (int i = 0; i < 4; ++i)
        wo[i] = ((unsigned int)f2bf(acc[2 * i + 1] + ac2[2 * i + 1]) << 16) |
                 (unsigned int)f2bf(acc[2 * i] + ac2[2 * i]);
    *(uint4*)(dbuf + (size_t)wid * 512 + lane * 8) = w4;
}

// ---------------- fallback aggr (interleaved U, deg-recompute; proven round-12) -------
template<int RELU>
__global__ void k_aggr(unsigned short* U, const int* __restrict__ rowptr,
                       const int* __restrict__ esrc, const int* __restrict__ deg,
                       const float* __restrict__ bias, int M) {
    int wid  = (blockIdx.x * 256 + threadIdx.x) >> 6;
    int lane = threadIdx.x & 63;
    if (wid >= M) return;
    int e0 = rowptr[wid], e1 = rowptr[wid + 1];
    if (RELU == 0 && e0 == e1) return;

    unsigned short* u0 = U + (size_t)wid * 1024 + lane * 8;
    uint4 v0 = *(const uint4*)u0;
    unsigned int a0[4] = {v0.x, v0.y, v0.z, v0.w};
    float acc[8];
    #pragma unroll
    for (int i = 0; i < 4; ++i) {
        acc[2 * i]     = bf2f((unsigned short)(a0[i] & 0xffffu));
        acc[2 * i + 1] = bf2f((unsigned short)(a0[i] >> 16));
    }
    if (e0 < e1) {
        int dd = deg[wid];
        float dr = dd > 0 ? rsqrtf((float)dd) : 0.f;
        for (int e = e0; e < e1; ++e) {
            int s = esrc[e];
            float we = -dr * rsqrtf((float)deg[s]);
            const uint4 v = *(const uint4*)(U + (size_t)s * 1024 + 512 + lane * 8);
            unsigned int uu[4] = {v.x, v.y, v.z, v.w};
            #pragma unroll
            for (int i = 0; i < 4; ++i) {
                acc[2 * i]     += we * bf2f((unsigned short)(uu[i] & 0xffffu));
                acc[2 * i + 1] += we * bf2f((unsigned short)(uu[i] >> 16));
            }
        }
    }
    if (RELU) {
        float4 c0 = *(const float4*)(bias + lane * 8);
        float4 c1 = *(const float4*)(bias + lane * 8 + 4);
        float bb[8] = {c0.x,c0.y,c0.z,c0.w,c1.x,c1.y,c1.z,c1.w};
        #pragma unroll
        for (int i = 0; i < 8; ++i) {
            float f = acc[i] + bb[i];
            acc[i] = f > 0.f ? f : 0.f;
        }
    }
    uint4 w4;
    unsigned int* wo = (unsigned int*)&w4;
    #pragma unroll
    for (int i = 0; i < 4; ++i)
        wo[i] = ((unsigned int)f2bf(acc[2 * i + 1]) << 16) | (unsigned int)f2bf(acc[2 * i]);
    *(uint4*)u0 = w4;
}

// ---------------- fallback final (interleaved U) ----------------
__global__ void k_final(const unsigned short* __restrict__ U, const float* __restrict__ b2,
                        const float* __restrict__ Wl, const float* __restrict__ bl,
                        float* __restrict__ out, int M) {
    int wid  = (blockIdx.x * 256 + threadIdx.x) >> 6;
    int lane = threadIdx.x & 63;
    if (wid >= M) return;
    const uint4 v = *(const uint4*)(U + (size_t)wid * 1024 + lane * 8);
    float4 c0 = *(const float4*)(b2 + lane * 8);
    float4 c1 = *(const float4*)(b2 + lane * 8 + 4);
    float bb[8] = {c0.x,c0.y,c0.z,c0.w,c1.x,c1.y,c1.z,c1.w};
    const float4* Wp = reinterpret_cast<const float4*>(Wl + lane * 16);
    float4 w0 = Wp[0], w1 = Wp[1], w2 = Wp[2], w3 = Wp[3];
    float wv[16] = {w0.x, w0.y, w0.z, w0.w, w1.x, w1.y, w1.z, w1.w,
                    w2.x, w2.y, w2.z, w2.w, w3.x, w3.y, w3.z, w3.w};
    unsigned int uu[4] = {v.x, v.y, v.z, v.w};
    float s0 = 0.f, s1 = 0.f;
    #pragma unroll
    for (int j = 0; j < 4; ++j) {
        float f0 = bf2f((unsigned short)(uu[j] & 0xffffu)) + bb[2 * j];
        float f1 = bf2f((unsigned short)(uu[j] >> 16))     + bb[2 * j + 1];
        f0 = f0 > 0.f ? f0 : 0.f;
        f1 = f1 > 0.f ? f1 : 0.f;
        s0 += f0 * wv[4 * j + 0];
        s1 += f0 * wv[4 * j + 1];
        s0 += f1 * wv[4 * j + 2];
        s1 += f1 * wv[4 * j + 3];
    }
    #pragma unroll
    for (int off = 32; off; off >>= 1) {
        s0 += __shfl_xor(s0, off, 64);
        s1 += __shfl_xor(s1, off, 64);
    }
    if (lane == 0) {
        out[2 * (size_t)wid]     = s0 + bl[0];
        out[2 * (size_t)wid + 1] = s1 + bl[1];
    }
}

extern "C" void kernel_launch(void* const* d_in, const int* in_sizes, int n_in,
                              void* d_out, int out_size, void* d_ws, size_t ws_size,
                              hipStream_t stream) {
    const float* x    = (const float*)d_in[0];
    const int*   ei   = (const int*)d_in[1];
    const float* W1_0 = (const float*)d_in[2];
    const float* W1_1 = (const float*)d_in[3];
    const float* b1   = (const float*)d_in[4];
    const float* W2_0 = (const float*)d_in[5];
    const float* W2_1 = (const float*)d_in[6];
    const float* b2   = (const float*)d_in[7];
    const float* Wl   = (const float*)d_in[8];
    const float* bl   = (const float*)d_in[9];
    const int* src = ei;
    const int* dst = ei + NEDGES;
    float* out = (float*)d_out;

    char* ws = (char*)d_ws;
    size_t off = 0;
    auto alloc = [&](size_t bytes) -> void* {
        void* p = ws + off;
        off += (bytes + 255) & ~(size_t)255;
        return p;
    };
    int*            deg    = (int*)alloc((size_t)NNODES * 4);
    int*            cnt    = (int*)alloc((size_t)NNODES * 4);
    int*            rowptr = (int*)alloc((size_t)(NNODES + 1) * 4);
    int*            btot   = (int*)alloc((size_t)NB * 4);
    unsigned short* P1     = (unsigned short*)alloc((size_t)2 * K1P * HID * 2);
    unsigned short* P2     = (unsigned short*)alloc((size_t)2 * HID * HID * 2);
    unsigned short* Hbuf   = (unsigned short*)alloc((size_t)MPAD * 1024 * 2);
    unsigned short* H0 = Hbuf;                        // fast path: dense [MPAD x 512]
    unsigned short* H1 = Hbuf + (size_t)MPAD * 512;   // fast path: dense [MPAD x 512]
    unsigned short* U  = Hbuf;                        // fallback: interleaved [MPAD x 1024]

    bool esrc_ws = (off + (size_t)NEDGES * 8 <= ws_size);
    int*   esrc = esrc_ws ? (int*)alloc((size_t)NEDGES * 4)   : (int*)d_out;
    float* ew   = esrc_ws ? (float*)alloc((size_t)NEDGES * 4) : nullptr;
    bool have_xb = (off + (size_t)MPAD * K1P * 2 <= ws_size);
    unsigned short* xb = have_xb ? (unsigned short*)alloc((size_t)MPAD * K1P * 2) : nullptr;

    hipMemsetAsync(deg, 0, (size_t)NNODES * 4, stream);
    hipMemsetAsync(cnt, 0, (size_t)NNODES * 4, stream);

    // CSR build + degrees + edge weights (+ out=bl init on fast path; E == 2*NNODES)
    k_deg    <<<(NEDGES + 255) / 256, 256, 0, stream>>>(src, dst, deg, cnt, NEDGES);
    k_scan1  <<<NB, 256, 0, stream>>>(cnt, btot, NNODES);
    k_scan2  <<<1, 1024, 0, stream>>>(btot, NB);
    k_scan3  <<<NB, 256, 0, stream>>>(cnt, btot, rowptr, NNODES, NEDGES);
    k_scatter<<<(NEDGES + 255) / 256, 256, 0, stream>>>(src, dst, rowptr, cnt, deg, esrc,
                                                        ew, esrc_ws ? out : nullptr, bl, NEDGES);

    // weight panels
    k_buildP1<<<(2 * K1P * HID + 255) / 256, 256, 0, stream>>>(W1_0, W1_1, P1);
    if (esrc_ws) {
        k_buildP2cat<<<(1024 * HID + 255) / 256, 256, 0, stream>>>(W2_0, W2_1, P2);
    } else {
        const int pg2 = (HID * HID + 255) / 256;
        k_buildP<<<pg2, 256, 0, stream>>>(W2_0, P2, HID, HID);
        k_buildP<<<pg2, 256, 0, stream>>>(W2_1, P2 + (size_t)HID * HID, HID, HID);
    }

    const int nblk = MPAD / 128;  // 1563

    if (esrc_ws && have_xb) {
        // fast path: dense halves H0 (panel-0 result -> h1) and H1 (panel-1 -> prop)
        k_xcvt<<<(int)(((long)NNODES * K1P / 8 + 255) / 256), 256, 0, stream>>>(x, xb);
        k_gemms<K1P, K1P, 8><<<8 * nblk, 256, 0, stream>>>(xb, P1, H0, H1, 512, 512, 0, 0);
        k_aggrh1<<<NNODES / 4, 256, 0, stream>>>(H0, H1, rowptr, esrc, ew, b1, NNODES);
        k_aggrh2<<<NNODES / 4, 256, 0, stream>>>(H1, H0, rowptr, esrc, ew, NNODES);
        k_gemmf<<<4 * nblk, 256, 0, stream>>>(H0, H1, P2, b2, Wl, out);
    } else {
        // fallback: interleaved-U path (round-12 proven)
        if (have_xb) {
            k_xcvt<<<(int)(((long)NNODES * K1P / 8 + 255) / 256), 256, 0, stream>>>(x, xb);
            k_gemms<K1P, K1P, 8><<<8 * nblk, 256, 0, stream>>>(xb, P1, U, U, 1024, 1024, 0, 512);
        } else {
            k_gemm0<<<nblk, 512, 0, stream>>>(x, P1, U, 0, NNODES);
            k_gemm0<<<nblk, 512, 0, stream>>>(x, P1 + (size_t)K1P * HID, U, 512, NNODES);
        }
        k_aggr<1><<<NNODES / 4, 256, 0, stream>>>(U, rowptr, esrc, deg, b1, NNODES);
        k_gemms<HID, 1024, 4><<<4 * nblk, 256, 0, stream>>>(U, P2 + (size_t)HID * HID,
                                                            U, U, 1024, 1024, 512, 512);
        k_gemmw<<<nblk, 512, 0, stream>>>(U, P2, U, 0, NNODES);
        k_aggr<0><<<NNODES / 4, 256, 0, stream>>>(U, rowptr, esrc, deg, nullptr, NNODES);
        k_final<<<NNODES / 4, 256, 0, stream>>>(U, b2, Wl, bl, out, NNODES);
    }
}